// Round 1
// baseline (1411.500 us; speedup 1.0000x reference)
//
#include <hip/hip_runtime.h>
#include <math.h>

#define NN 50000
#define NE 640000
#define F  32
#define KCH 9
#define CUT 5.0f

// Gaunt-contraction constants (analytic, matches reference's lstsq fit)
#define C13 (1.0f/3.0f)
#define C23 (2.0f/3.0f)
#define C15 0.2f
#define C25 0.4f
#define C17 (1.0f/7.0f)
#define C27 (2.0f/7.0f)
#define IS3 0.5773502691896258f   /* 1/sqrt(3) */
#define S35 0.3464101615137755f   /* sqrt(3)/5 */
#define S37 0.2474358296526968f   /* sqrt(3)/7 */
#define S3  1.7320508075688772f

__global__ __launch_bounds__(256) void init_row0(const float* __restrict__ embed,
                                                 const int* __restrict__ Z,
                                                 float* __restrict__ x) {
    int idx = blockIdx.x * 256 + threadIdx.x;   // n*32 + f
    if (idx >= NN * F) return;
    int n = idx >> 5, f = idx & 31;
    x[(size_t)n * KCH * F + f] = embed[Z[n] * F + f];
}

template<int LAST>
__global__ __launch_bounds__(256) void edge_kernel(const float* __restrict__ dr,
                                                   const int* __restrict__ idx_i,
                                                   const int* __restrict__ idx_j,
                                                   const float* __restrict__ rad_w_iter, // [3][8][32]
                                                   const float* __restrict__ x,
                                                   float* __restrict__ m) {
    __shared__ float rw[3 * 8 * F];
    for (int t = threadIdx.x; t < 3 * 8 * F; t += 256) rw[t] = rad_w_iter[t];
    __syncthreads();

    int grp = threadIdx.x >> 5;
    int f   = threadIdx.x & 31;
    int e   = blockIdx.x * 8 + grp;

    int ni = idx_i[e], nj = idx_j[e];
    float dx = dr[e * 3 + 0], dy = dr[e * 3 + 1], dz = dr[e * 3 + 2];
    float r2 = dx * dx + dy * dy + dz * dz;
    float r  = sqrtf(r2);
    if (ni == nj || r >= CUT) return;

    float inv = 1.0f / fmaxf(r, 1e-9f);
    float ux = dx * inv, uy = dy * inv, uz = dz * inv;

    float Y[9];
    Y[0] = 1.0f; Y[1] = uy; Y[2] = uz; Y[3] = ux;
    Y[4] = S3 * ux * uy; Y[5] = S3 * uy * uz;
    Y[6] = 0.5f * (3.0f * uz * uz - 1.0f);
    Y[7] = S3 * ux * uz; Y[8] = 0.5f * S3 * (ux * ux - uy * uy);

    // Bernstein radial basis * smooth cutoff
    float ur = r / (1.0f + r);
    float vr = 1.0f - ur;
    float up[8], vp[8];
    up[0] = 1.0f; vp[0] = 1.0f;
    #pragma unroll
    for (int kk = 1; kk < 8; ++kk) { up[kk] = up[kk - 1] * ur; vp[kk] = vp[kk - 1] * vr; }
    const float binom[8] = {1.f, 7.f, 21.f, 35.f, 35.f, 21.f, 7.f, 1.f};
    float denom = CUT * CUT - r2;
    float cut = expf(-r2 / fmaxf(denom, 1e-12f));
    float rad[8];
    #pragma unroll
    for (int kk = 0; kk < 8; ++kk) rad[kk] = binom[kk] * up[kk] * vp[7 - kk] * cut;

    // g[l] = sum_b rad[b] * rad_w[l][b][f]
    float g0 = 0.f, g1 = 0.f, g2 = 0.f;
    #pragma unroll
    for (int b = 0; b < 8; ++b) {
        float rb = rad[b];
        g0 = fmaf(rb, rw[(0 * 8 + b) * F + f], g0);
        g1 = fmaf(rb, rw[(1 * 8 + b) * F + f], g1);
        g2 = fmaf(rb, rw[(2 * 8 + b) * F + f], g2);
    }

    const float* xp = x + (size_t)nj * KCH * F + f;
    float xe[9];
    #pragma unroll
    for (int a = 0; a < 9; ++a) xe[a] = xp[a * F];

    float w[9];
    w[0] = Y[0] * g0;
    w[1] = Y[1] * g1; w[2] = Y[2] * g1; w[3] = Y[3] * g1;
    w[4] = Y[4] * g2; w[5] = Y[5] * g2; w[6] = Y[6] * g2;
    w[7] = Y[7] * g2; w[8] = Y[8] * g2;

    float d0 = xe[0] * w[0], d1 = xe[1] * w[1], d2 = xe[2] * w[2], d3 = xe[3] * w[3];
    float d4 = xe[4] * w[4], d5 = xe[5] * w[5], d6 = xe[6] * w[6], d7 = xe[7] * w[7];
    float d8 = xe[8] * w[8];
    #define T(a, b) (xe[a] * w[b] + xe[b] * w[a])

    float y0 = d0 + C13 * (d1 + d2 + d3) + C15 * (d4 + d5 + d6 + d7 + d8);
    if (LAST) {
        unsafeAtomicAdd(m + (size_t)ni * F + f, y0);
    } else {
        float y1 = T(0,1) - C15 * T(1,6) - S35 * T(1,8) + S35 * T(2,5) + S35 * T(3,4);
        float y2 = T(0,2) + S35 * T(1,5) + C25 * T(2,6) + S35 * T(3,7);
        float y3 = T(0,3) + S35 * T(1,4) + S35 * T(2,7) - C15 * T(3,6) + S35 * T(3,8);
        float y4 = T(0,4) + IS3 * T(1,3) - C27 * T(4,6) + S37 * T(5,7);
        float y5 = T(0,5) + IS3 * T(1,2) + S37 * T(4,7) + C17 * T(5,6) - S37 * T(5,8);
        float y6 = T(0,6) - C13 * d1 + C23 * d2 - C13 * d3
                 - C27 * d4 + C17 * d5 + C27 * d6 + C17 * d7 - C27 * d8;
        float y7 = T(0,7) + IS3 * T(2,3) + S37 * T(4,5) + C17 * T(6,7) + S37 * T(7,8);
        float y8 = T(0,8) - IS3 * d1 + IS3 * d3 - S37 * d5 + S37 * d7 - C27 * T(6,8);
        float* mp = m + (size_t)ni * KCH * F + f;
        unsafeAtomicAdd(mp + 0 * F, y0);
        unsafeAtomicAdd(mp + 1 * F, y1);
        unsafeAtomicAdd(mp + 2 * F, y2);
        unsafeAtomicAdd(mp + 3 * F, y3);
        unsafeAtomicAdd(mp + 4 * F, y4);
        unsafeAtomicAdd(mp + 5 * F, y5);
        unsafeAtomicAdd(mp + 6 * F, y6);
        unsafeAtomicAdd(mp + 7 * F, y7);
        unsafeAtomicAdd(mp + 8 * F, y8);
    }
    #undef T
}

// one thread per (node, k) row; weights fetched as wave-uniform scalar loads
__global__ __launch_bounds__(256) void node_full(float* __restrict__ x,
                                                 const float* __restrict__ m,
                                                 const float* __restrict__ w1,
                                                 const float* __restrict__ b1,
                                                 const float* __restrict__ w2,
                                                 const float* __restrict__ b2) {
    __shared__ float gs[28][33];
    int t = threadIdx.x;
    int slot = t / 9, k = t - slot * 9;
    int n = blockIdx.x * 28 + slot;
    bool valid = (t < 252) && (n < NN);

    float h[F], o1[F];
    if (valid) {
        const float4* xp = (const float4*)(x + ((size_t)n * KCH + k) * F);
        const float4* mp = (const float4*)(m + ((size_t)n * KCH + k) * F);
        #pragma unroll
        for (int j = 0; j < 8; ++j) {
            float4 a = xp[j], b = mp[j];
            h[4 * j + 0] = a.x + b.x; h[4 * j + 1] = a.y + b.y;
            h[4 * j + 2] = a.z + b.z; h[4 * j + 3] = a.w + b.w;
        }
        #pragma unroll
        for (int fo = 0; fo < F; ++fo) {
            float s = 0.f;
            #pragma unroll
            for (int fi = 0; fi < F; ++fi) s = fmaf(h[fi], w1[fi * F + fo], s);
            o1[fo] = s;
        }
        if (k == 0) {
            #pragma unroll
            for (int j = 0; j < F; ++j) {
                o1[j] += b1[j];
                gs[slot][j] = 1.0f / (1.0f + expf(-o1[j]));
            }
        }
    }
    __syncthreads();
    if (valid) {
        #pragma unroll
        for (int j = 0; j < F; ++j) h[j] = o1[j] * gs[slot][j];
        #pragma unroll
        for (int fo = 0; fo < F; ++fo) {
            float s = (k == 0) ? b2[fo] : 0.f;
            #pragma unroll
            for (int fi = 0; fi < F; ++fi) s = fmaf(h[fi], w2[fi * F + fo], s);
            o1[fo] = s;
        }
        float4* xw = (float4*)(x + ((size_t)n * KCH + k) * F);
        #pragma unroll
        for (int j = 0; j < 8; ++j) {
            float4 a = xw[j];
            a.x += o1[4 * j + 0]; a.y += o1[4 * j + 1];
            a.z += o1[4 * j + 2]; a.w += o1[4 * j + 3];
            xw[j] = a;
        }
    }
}

__global__ __launch_bounds__(256) void node_last(const float* __restrict__ x,
                                                 const float* __restrict__ m1,
                                                 const float* __restrict__ w1,
                                                 const float* __restrict__ b1,
                                                 const float* __restrict__ w2,
                                                 const float* __restrict__ b2,
                                                 float* __restrict__ out) {
    int n = blockIdx.x * 256 + threadIdx.x;
    if (n >= NN) return;
    float h[F], o1[F];
    const float4* xp = (const float4*)(x + (size_t)n * KCH * F);   // row k=0
    const float4* mp = (const float4*)(m1 + (size_t)n * F);
    #pragma unroll
    for (int j = 0; j < 8; ++j) {
        float4 a = xp[j], b = mp[j];
        h[4 * j + 0] = a.x + b.x; h[4 * j + 1] = a.y + b.y;
        h[4 * j + 2] = a.z + b.z; h[4 * j + 3] = a.w + b.w;
    }
    #pragma unroll
    for (int fo = 0; fo < F; ++fo) {
        float s = 0.f;
        #pragma unroll
        for (int fi = 0; fi < F; ++fi) s = fmaf(h[fi], w1[fi * F + fo], s);
        s += b1[fo];
        o1[fo] = s;
    }
    #pragma unroll
    for (int j = 0; j < F; ++j) {
        float g = 1.0f / (1.0f + expf(-o1[j]));
        h[j] = o1[j] * g;
    }
    #pragma unroll
    for (int fo = 0; fo < F; ++fo) {
        float s = b2[fo];
        #pragma unroll
        for (int fi = 0; fi < F; ++fi) s = fmaf(h[fi], w2[fi * F + fo], s);
        o1[fo] = s;
    }
    #pragma unroll
    for (int j = 0; j < F; ++j)
        out[(size_t)n * F + j] = x[(size_t)n * KCH * F + j] + o1[j];
}

extern "C" void kernel_launch(void* const* d_in, const int* in_sizes, int n_in,
                              void* d_out, int out_size, void* d_ws, size_t ws_size,
                              hipStream_t stream) {
    (void)in_sizes; (void)n_in; (void)out_size; (void)ws_size;
    const float* dr    = (const float*)d_in[0];
    const float* embed = (const float*)d_in[1];
    const float* rad_w = (const float*)d_in[2];
    const float* d1w   = (const float*)d_in[3];
    const float* d1b   = (const float*)d_in[4];
    const float* d2w   = (const float*)d_in[5];
    const float* d2b   = (const float*)d_in[6];
    const int*   Z     = (const int*)d_in[7];
    const int*   nidx  = (const int*)d_in[8];
    const int* idx_i = nidx;
    const int* idx_j = nidx + NE;

    float* x = (float*)d_ws;
    float* m = x + (size_t)NN * KCH * F;
    float* outp = (float*)d_out;

    size_t XB = (size_t)NN * KCH * F * sizeof(float);

    hipMemsetAsync(x, 0, XB, stream);
    init_row0<<<(NN * F + 255) / 256, 256, 0, stream>>>(embed, Z, x);

    for (int i = 0; i < 3; ++i) {
        const float* rwi = rad_w + (size_t)i * 3 * 8 * F;
        const float* w1 = d1w + (size_t)i * F * F;
        const float* b1 = d1b + (size_t)i * F;
        const float* w2 = d2w + (size_t)i * F * F;
        const float* b2 = d2b + (size_t)i * F;
        if (i < 2) {
            hipMemsetAsync(m, 0, XB, stream);
            edge_kernel<0><<<NE / 8, 256, 0, stream>>>(dr, idx_i, idx_j, rwi, x, m);
            node_full<<<(NN + 27) / 28, 256, 0, stream>>>(x, m, w1, b1, w2, b2);
        } else {
            hipMemsetAsync(m, 0, (size_t)NN * F * sizeof(float), stream);
            edge_kernel<1><<<NE / 8, 256, 0, stream>>>(dr, idx_i, idx_j, rwi, x, m);
            node_last<<<(NN + 255) / 256, 256, 0, stream>>>(x, m, w1, b1, w2, b2, outp);
        }
    }
}

// Round 2
// 956.951 us; speedup vs baseline: 1.4750x; 1.4750x over previous
//
#include <hip/hip_runtime.h>
#include <math.h>

#define NN 50000
#define NE 640000
#define F  32
#define KCH 9
#define CUT 5.0f

// Gaunt-contraction constants (analytic, matches reference's lstsq fit)
#define C13 (1.0f/3.0f)
#define C23 (2.0f/3.0f)
#define C15 0.2f
#define C25 0.4f
#define C17 (1.0f/7.0f)
#define C27 (2.0f/7.0f)
#define IS3 0.5773502691896258f   /* 1/sqrt(3) */
#define S35 0.3464101615137755f   /* sqrt(3)/5 */
#define S37 0.2474358296526968f   /* sqrt(3)/7 */
#define S3  1.7320508075688772f

__global__ __launch_bounds__(256) void init_x(const float* __restrict__ embed,
                                              const int* __restrict__ Z,
                                              float* __restrict__ x) {
    int idx = blockIdx.x * 256 + threadIdx.x;   // n*32 + f
    if (idx >= NN * F) return;
    int n = idx >> 5, f = idx & 31;
    float v = embed[Z[n] * F + f];
    float* xp = x + (size_t)n * KCH * F + f;
    xp[0] = v;
    #pragma unroll
    for (int a = 1; a < KCH; ++a) xp[a * F] = 0.f;
}

__global__ __launch_bounds__(256) void hist_kernel(const int* __restrict__ idx_i,
                                                   int* __restrict__ cnt) {
    int e = blockIdx.x * 256 + threadIdx.x;
    if (e < NE) atomicAdd(&cnt[idx_i[e]], 1);
}

#define SCAN_T 1024
#define SCAN_C ((NN + SCAN_T - 1) / SCAN_T)   // 49

__global__ __launch_bounds__(SCAN_T) void scan_kernel(const int* __restrict__ cnt,
                                                      int* __restrict__ offs,
                                                      int* __restrict__ head) {
    __shared__ int ps[SCAN_T];
    int t = threadIdx.x;
    int b = t * SCAN_C;
    int e = min(b + SCAN_C, NN);
    int s = 0;
    for (int i = b; i < e; ++i) s += cnt[i];
    ps[t] = s;
    __syncthreads();
    for (int off = 1; off < SCAN_T; off <<= 1) {
        int v = (t >= off) ? ps[t - off] : 0;
        __syncthreads();
        ps[t] += v;
        __syncthreads();
    }
    int run = (t == 0) ? 0 : ps[t - 1];
    for (int i = b; i < e; ++i) { int c = cnt[i]; offs[i] = run; head[i] = run; run += c; }
    if (t == SCAN_T - 1) offs[NN] = NE;
}

__global__ __launch_bounds__(256) void fill_kernel(const int* __restrict__ idx_i,
                                                   const int* __restrict__ idx_j,
                                                   const float* __restrict__ dr,
                                                   int* __restrict__ head,
                                                   float4* __restrict__ erec) {
    int e = blockIdx.x * 256 + threadIdx.x;
    if (e >= NE) return;
    int ni = idx_i[e];
    int p = atomicAdd(&head[ni], 1);
    float4 rec;
    rec.x = dr[3 * e + 0];
    rec.y = dr[3 * e + 1];
    rec.z = dr[3 * e + 2];
    rec.w = __int_as_float(idx_j[e]);
    erec[p] = rec;
}

// one wave64 per destination node; half-wave = one edge, lane&31 = feature
template<int LAST>
__global__ __launch_bounds__(256) void gather_kernel(const float4* __restrict__ erec,
                                                     const float* __restrict__ rw_iter, // [3][8][32]
                                                     const float* __restrict__ x,
                                                     const int* __restrict__ offs,
                                                     float* __restrict__ m) {
    int lane = threadIdx.x & 63;
    int wid  = threadIdx.x >> 6;
    int half = lane >> 5;
    int f    = lane & 31;
    int n    = blockIdx.x * 4 + wid;   // grid = NN/4 exactly

    float rwv[24];
    #pragma unroll
    for (int lb = 0; lb < 24; ++lb) rwv[lb] = rw_iter[lb * F + f];

    int start = offs[n], end = offs[n + 1];

    constexpr int NACC = LAST ? 1 : KCH;
    float acc[NACC];
    #pragma unroll
    for (int a = 0; a < NACC; ++a) acc[a] = 0.f;

    for (int t = start + half; t < end; t += 2) {
        float4 rec = erec[t];
        int nj = __float_as_int(rec.w);
        float dx = rec.x, dy = rec.y, dz = rec.z;
        float r2 = fmaf(dx, dx, fmaf(dy, dy, dz * dz));
        float r  = sqrtf(r2);
        float inv = 1.0f / fmaxf(r, 1e-9f);
        float ux = dx * inv, uy = dy * inv, uz = dz * inv;

        float cut = expf(-r2 / fmaxf(CUT * CUT - r2, 1e-12f));
        if (nj == n) cut = 0.f;

        float ur = r / (1.0f + r), vr = 1.0f - ur;
        float up2 = ur * ur,  up3 = up2 * ur, up4 = up3 * ur, up5 = up4 * ur, up6 = up5 * ur, up7 = up6 * ur;
        float vp2 = vr * vr,  vp3 = vp2 * vr, vp4 = vp3 * vr, vp5 = vp4 * vr, vp6 = vp5 * vr, vp7 = vp6 * vr;
        float rad[8];
        rad[0] = vp7;
        rad[1] = 7.f  * ur  * vp6;
        rad[2] = 21.f * up2 * vp5;
        rad[3] = 35.f * up3 * vp4;
        rad[4] = 35.f * up4 * vp3;
        rad[5] = 21.f * up5 * vp2;
        rad[6] = 7.f  * up6 * vr;
        rad[7] = up7;

        float g0 = 0.f, g1 = 0.f, g2 = 0.f;
        #pragma unroll
        for (int b = 0; b < 8; ++b) {
            g0 = fmaf(rad[b], rwv[b],      g0);
            g1 = fmaf(rad[b], rwv[8 + b],  g1);
            g2 = fmaf(rad[b], rwv[16 + b], g2);
        }
        g0 *= cut; g1 *= cut; g2 *= cut;

        const float* xp = x + (size_t)nj * KCH * F + f;
        float xe[9];
        #pragma unroll
        for (int a = 0; a < 9; ++a) xe[a] = xp[a * F];

        float w[9];
        w[0] = g0;
        w[1] = uy * g1; w[2] = uz * g1; w[3] = ux * g1;
        w[4] = S3 * ux * uy * g2;
        w[5] = S3 * uy * uz * g2;
        w[6] = 0.5f * (3.0f * uz * uz - 1.0f) * g2;
        w[7] = S3 * ux * uz * g2;
        w[8] = 0.5f * S3 * (ux * ux - uy * uy) * g2;

        float d0 = xe[0]*w[0], d1 = xe[1]*w[1], d2 = xe[2]*w[2], d3 = xe[3]*w[3];
        float d4 = xe[4]*w[4], d5 = xe[5]*w[5], d6 = xe[6]*w[6], d7 = xe[7]*w[7];
        float d8 = xe[8]*w[8];

        acc[0] += d0 + C13 * (d1 + d2 + d3) + C15 * (d4 + d5 + d6 + d7 + d8);
        if (!LAST) {
            #define T(a, b) (xe[a] * w[b] + xe[b] * w[a])
            acc[1] += T(0,1) - C15 * T(1,6) - S35 * T(1,8) + S35 * T(2,5) + S35 * T(3,4);
            acc[2] += T(0,2) + S35 * T(1,5) + C25 * T(2,6) + S35 * T(3,7);
            acc[3] += T(0,3) + S35 * T(1,4) + S35 * T(2,7) - C15 * T(3,6) + S35 * T(3,8);
            acc[4] += T(0,4) + IS3 * T(1,3) - C27 * T(4,6) + S37 * T(5,7);
            acc[5] += T(0,5) + IS3 * T(1,2) + S37 * T(4,7) + C17 * T(5,6) - S37 * T(5,8);
            acc[6] += T(0,6) - C13 * d1 + C23 * d2 - C13 * d3
                    - C27 * d4 + C17 * d5 + C27 * d6 + C17 * d7 - C27 * d8;
            acc[7] += T(0,7) + IS3 * T(2,3) + S37 * T(4,5) + C17 * T(6,7) + S37 * T(7,8);
            acc[8] += T(0,8) - IS3 * d1 + IS3 * d3 - S37 * d5 + S37 * d7 - C27 * T(6,8);
            #undef T
        }
    }

    #pragma unroll
    for (int a = 0; a < NACC; ++a) acc[a] += __shfl_xor(acc[a], 32);

    if (half == 0) {
        if (LAST) {
            m[(size_t)n * F + f] = acc[0];
        } else {
            float* mp = m + (size_t)n * KCH * F + f;
            #pragma unroll
            for (int a = 0; a < KCH; ++a) mp[a * F] = acc[a];
        }
    }
}

// one thread per (node, k) row; weights fetched as wave-uniform scalar loads
__global__ __launch_bounds__(256) void node_full(float* __restrict__ x,
                                                 const float* __restrict__ m,
                                                 const float* __restrict__ w1,
                                                 const float* __restrict__ b1,
                                                 const float* __restrict__ w2,
                                                 const float* __restrict__ b2) {
    __shared__ float gs[28][33];
    int t = threadIdx.x;
    int slot = t / 9, k = t - slot * 9;
    int n = blockIdx.x * 28 + slot;
    bool valid = (t < 252) && (n < NN);

    float h[F], o1[F];
    if (valid) {
        const float4* xp = (const float4*)(x + ((size_t)n * KCH + k) * F);
        const float4* mp = (const float4*)(m + ((size_t)n * KCH + k) * F);
        #pragma unroll
        for (int j = 0; j < 8; ++j) {
            float4 a = xp[j], b = mp[j];
            h[4 * j + 0] = a.x + b.x; h[4 * j + 1] = a.y + b.y;
            h[4 * j + 2] = a.z + b.z; h[4 * j + 3] = a.w + b.w;
        }
        #pragma unroll
        for (int fo = 0; fo < F; ++fo) {
            float s = 0.f;
            #pragma unroll
            for (int fi = 0; fi < F; ++fi) s = fmaf(h[fi], w1[fi * F + fo], s);
            o1[fo] = s;
        }
        if (k == 0) {
            #pragma unroll
            for (int j = 0; j < F; ++j) {
                o1[j] += b1[j];
                gs[slot][j] = 1.0f / (1.0f + expf(-o1[j]));
            }
        }
    }
    __syncthreads();
    if (valid) {
        #pragma unroll
        for (int j = 0; j < F; ++j) h[j] = o1[j] * gs[slot][j];
        #pragma unroll
        for (int fo = 0; fo < F; ++fo) {
            float s = (k == 0) ? b2[fo] : 0.f;
            #pragma unroll
            for (int fi = 0; fi < F; ++fi) s = fmaf(h[fi], w2[fi * F + fo], s);
            o1[fo] = s;
        }
        float4* xw = (float4*)(x + ((size_t)n * KCH + k) * F);
        #pragma unroll
        for (int j = 0; j < 8; ++j) {
            float4 a = xw[j];
            a.x += o1[4 * j + 0]; a.y += o1[4 * j + 1];
            a.z += o1[4 * j + 2]; a.w += o1[4 * j + 3];
            xw[j] = a;
        }
    }
}

__global__ __launch_bounds__(256) void node_last(const float* __restrict__ x,
                                                 const float* __restrict__ m1,
                                                 const float* __restrict__ w1,
                                                 const float* __restrict__ b1,
                                                 const float* __restrict__ w2,
                                                 const float* __restrict__ b2,
                                                 float* __restrict__ out) {
    int n = blockIdx.x * 256 + threadIdx.x;
    if (n >= NN) return;
    float h[F], o1[F];
    const float4* xp = (const float4*)(x + (size_t)n * KCH * F);   // row k=0
    const float4* mp = (const float4*)(m1 + (size_t)n * F);
    #pragma unroll
    for (int j = 0; j < 8; ++j) {
        float4 a = xp[j], b = mp[j];
        h[4 * j + 0] = a.x + b.x; h[4 * j + 1] = a.y + b.y;
        h[4 * j + 2] = a.z + b.z; h[4 * j + 3] = a.w + b.w;
    }
    #pragma unroll
    for (int fo = 0; fo < F; ++fo) {
        float s = 0.f;
        #pragma unroll
        for (int fi = 0; fi < F; ++fi) s = fmaf(h[fi], w1[fi * F + fo], s);
        s += b1[fo];
        o1[fo] = s;
    }
    #pragma unroll
    for (int j = 0; j < F; ++j) {
        float g = 1.0f / (1.0f + expf(-o1[j]));
        h[j] = o1[j] * g;
    }
    #pragma unroll
    for (int fo = 0; fo < F; ++fo) {
        float s = b2[fo];
        #pragma unroll
        for (int fi = 0; fi < F; ++fi) s = fmaf(h[fi], w2[fi * F + fo], s);
        o1[fo] = s;
    }
    #pragma unroll
    for (int j = 0; j < F; ++j)
        out[(size_t)n * F + j] = x[(size_t)n * KCH * F + j] + o1[j];
}

extern "C" void kernel_launch(void* const* d_in, const int* in_sizes, int n_in,
                              void* d_out, int out_size, void* d_ws, size_t ws_size,
                              hipStream_t stream) {
    (void)in_sizes; (void)n_in; (void)out_size; (void)ws_size;
    const float* dr    = (const float*)d_in[0];
    const float* embed = (const float*)d_in[1];
    const float* rad_w = (const float*)d_in[2];
    const float* d1w   = (const float*)d_in[3];
    const float* d1b   = (const float*)d_in[4];
    const float* d2w   = (const float*)d_in[5];
    const float* d2b   = (const float*)d_in[6];
    const int*   Z     = (const int*)d_in[7];
    const int*   nidx  = (const int*)d_in[8];
    const int* idx_i = nidx;
    const int* idx_j = nidx + NE;

    float* x = (float*)d_ws;
    float* m = x + (size_t)NN * KCH * F;
    int*   offs = (int*)(m + (size_t)NN * KCH * F);   // NN+1
    int*   head = offs + (NN + 1);                    // NN
    int*   cnt  = head + NN;                          // NN
    float4* erec = (float4*)(cnt + NN);               // NE (16B-aligned: offset from ws start is multiple of 16)
    float* outp = (float*)d_out;

    // CSR build
    hipMemsetAsync(cnt, 0, NN * sizeof(int), stream);
    hist_kernel<<<(NE + 255) / 256, 256, 0, stream>>>(idx_i, cnt);
    scan_kernel<<<1, SCAN_T, 0, stream>>>(cnt, offs, head);
    fill_kernel<<<(NE + 255) / 256, 256, 0, stream>>>(idx_i, idx_j, dr, head, erec);

    init_x<<<(NN * F + 255) / 256, 256, 0, stream>>>(embed, Z, x);

    for (int i = 0; i < 3; ++i) {
        const float* rwi = rad_w + (size_t)i * 3 * 8 * F;
        const float* w1 = d1w + (size_t)i * F * F;
        const float* b1 = d1b + (size_t)i * F;
        const float* w2 = d2w + (size_t)i * F * F;
        const float* b2 = d2b + (size_t)i * F;
        if (i < 2) {
            gather_kernel<0><<<NN / 4, 256, 0, stream>>>(erec, rwi, x, offs, m);
            node_full<<<(NN + 27) / 28, 256, 0, stream>>>(x, m, w1, b1, w2, b2);
        } else {
            gather_kernel<1><<<NN / 4, 256, 0, stream>>>(erec, rwi, x, offs, m);
            node_last<<<(NN + 255) / 256, 256, 0, stream>>>(x, m, w1, b1, w2, b2, outp);
        }
    }
}

// Round 3
// 828.866 us; speedup vs baseline: 1.7029x; 1.1545x over previous
//
#include <hip/hip_runtime.h>
#include <math.h>

#define NN 50000
#define NE 640000
#define F  32
#define KCH 9
#define CUT 5.0f

#define C13 (1.0f/3.0f)
#define C23 (2.0f/3.0f)
#define C15 0.2f
#define C25 0.4f
#define C17 (1.0f/7.0f)
#define C27 (2.0f/7.0f)
#define IS3 0.5773502691896258f   /* 1/sqrt(3) */
#define S35 0.3464101615137755f   /* sqrt(3)/5 */
#define S37 0.2474358296526968f   /* sqrt(3)/7 */
#define S3  1.7320508075688772f

__global__ __launch_bounds__(256) void init_x(const float* __restrict__ embed,
                                              const int* __restrict__ Z,
                                              float* __restrict__ x) {
    int idx = blockIdx.x * 256 + threadIdx.x;   // n*32 + f
    if (idx >= NN * F) return;
    int n = idx >> 5, f = idx & 31;
    float v = embed[Z[n] * F + f];
    float* xp = x + (size_t)n * KCH * F + f;
    xp[0] = v;
    #pragma unroll
    for (int a = 1; a < KCH; ++a) xp[a * F] = 0.f;
}

// count only LIVE edges (r < CUT, not self). Filter expression must match fill_kernel.
__global__ __launch_bounds__(256) void hist_kernel(const int* __restrict__ idx_i,
                                                   const int* __restrict__ idx_j,
                                                   const float* __restrict__ dr,
                                                   int* __restrict__ cnt) {
    int e = blockIdx.x * 256 + threadIdx.x;
    if (e >= NE) return;
    int ni = idx_i[e], nj = idx_j[e];
    float dx = dr[3 * e + 0], dy = dr[3 * e + 1], dz = dr[3 * e + 2];
    float r2 = fmaf(dx, dx, fmaf(dy, dy, dz * dz));
    if (ni != nj && r2 < CUT * CUT) atomicAdd(&cnt[ni], 1);
}

#define SCAN_T 1024
#define SCAN_C ((NN + SCAN_T - 1) / SCAN_T)   // 49

__global__ __launch_bounds__(SCAN_T) void scan_kernel(const int* __restrict__ cnt,
                                                      int* __restrict__ offs,
                                                      int* __restrict__ head) {
    __shared__ int ps[SCAN_T];
    int t = threadIdx.x;
    int b = t * SCAN_C;
    int e = min(b + SCAN_C, NN);
    int s = 0;
    for (int i = b; i < e; ++i) s += cnt[i];
    ps[t] = s;
    __syncthreads();
    for (int off = 1; off < SCAN_T; off <<= 1) {
        int v = (t >= off) ? ps[t - off] : 0;
        __syncthreads();
        ps[t] += v;
        __syncthreads();
    }
    int run = (t == 0) ? 0 : ps[t - 1];
    for (int i = b; i < e; ++i) { int c = cnt[i]; offs[i] = run; head[i] = run; run += c; }
    if (t == SCAN_T - 1) offs[NN] = ps[SCAN_T - 1];
}

// compact live edges + precompute geometry: rec = {nj, ux,uy,uz}, {rc0..3}, {rc4..7}
__global__ __launch_bounds__(256) void fill_kernel(const int* __restrict__ idx_i,
                                                   const int* __restrict__ idx_j,
                                                   const float* __restrict__ dr,
                                                   int* __restrict__ head,
                                                   float4* __restrict__ erec) {
    int e = blockIdx.x * 256 + threadIdx.x;
    if (e >= NE) return;
    int ni = idx_i[e], nj = idx_j[e];
    float dx = dr[3 * e + 0], dy = dr[3 * e + 1], dz = dr[3 * e + 2];
    float r2 = fmaf(dx, dx, fmaf(dy, dy, dz * dz));
    if (!(ni != nj && r2 < CUT * CUT)) return;

    float r = sqrtf(r2);
    float inv = 1.0f / fmaxf(r, 1e-9f);
    float ux = dx * inv, uy = dy * inv, uz = dz * inv;

    float cut = expf(-r2 / fmaxf(CUT * CUT - r2, 1e-12f));
    float ur = r / (1.0f + r), vr = 1.0f - ur;
    float up2 = ur * ur,  up3 = up2 * ur, up4 = up3 * ur, up5 = up4 * ur, up6 = up5 * ur, up7 = up6 * ur;
    float vp2 = vr * vr,  vp3 = vp2 * vr, vp4 = vp3 * vr, vp5 = vp4 * vr, vp6 = vp5 * vr, vp7 = vp6 * vr;

    int p = atomicAdd(&head[ni], 1);
    float4 r0, r1, r2v;
    r0.x = __int_as_float(nj); r0.y = ux; r0.z = uy; r0.w = uz;
    r1.x = cut * vp7;
    r1.y = cut * 7.f  * ur  * vp6;
    r1.z = cut * 21.f * up2 * vp5;
    r1.w = cut * 35.f * up3 * vp4;
    r2v.x = cut * 35.f * up4 * vp3;
    r2v.y = cut * 21.f * up5 * vp2;
    r2v.z = cut * 7.f  * up6 * vr;
    r2v.w = cut * up7;
    erec[(size_t)3 * p + 0] = r0;
    erec[(size_t)3 * p + 1] = r1;
    erec[(size_t)3 * p + 2] = r2v;
}

// one wave64 per node (persistent-wave stride); half-wave = one edge, lane&31 = feature
template<int LAST>
__global__ __launch_bounds__(256) void gather_kernel(const float4* __restrict__ erec,
                                                     const float* __restrict__ rw_iter, // [3][8][32]
                                                     const float* __restrict__ x,
                                                     const int* __restrict__ offs,
                                                     float* __restrict__ m) {
    const int NWAVES = 2048 * 4;
    int lane = threadIdx.x & 63;
    int wid  = threadIdx.x >> 6;
    int half = lane >> 5;
    int f    = lane & 31;
    int gw   = blockIdx.x * 4 + wid;

    float rwv[24];
    #pragma unroll
    for (int lb = 0; lb < 24; ++lb) rwv[lb] = rw_iter[lb * F + f];

    constexpr int NACC = LAST ? 1 : KCH;

    for (int n = gw; n < NN; n += NWAVES) {
        int start = offs[n], end = offs[n + 1];

        float acc[NACC];
        #pragma unroll
        for (int a = 0; a < NACC; ++a) acc[a] = 0.f;

        int t = start + half;
        float4 c0 = {}, c1 = {}, c2 = {};
        float4 n0 = {}, n1 = {}, n2 = {};
        if (t < end) {
            c0 = erec[(size_t)3 * t + 0];
            c1 = erec[(size_t)3 * t + 1];
            c2 = erec[(size_t)3 * t + 2];
        }
        while (t < end) {
            int tn = t + 2;
            if (tn < end) {
                n0 = erec[(size_t)3 * tn + 0];
                n1 = erec[(size_t)3 * tn + 1];
                n2 = erec[(size_t)3 * tn + 2];
            }
            int nj = __float_as_int(c0.x);
            const float* xp = x + (size_t)nj * KCH * F + f;
            float xe[9];
            #pragma unroll
            for (int a = 0; a < 9; ++a) xe[a] = xp[a * F];

            float ux = c0.y, uy = c0.z, uz = c0.w;
            float g0 = 0.f, g1 = 0.f, g2 = 0.f;
            g0 = fmaf(c1.x, rwv[0], g0);  g1 = fmaf(c1.x, rwv[8],  g1);  g2 = fmaf(c1.x, rwv[16], g2);
            g0 = fmaf(c1.y, rwv[1], g0);  g1 = fmaf(c1.y, rwv[9],  g1);  g2 = fmaf(c1.y, rwv[17], g2);
            g0 = fmaf(c1.z, rwv[2], g0);  g1 = fmaf(c1.z, rwv[10], g1);  g2 = fmaf(c1.z, rwv[18], g2);
            g0 = fmaf(c1.w, rwv[3], g0);  g1 = fmaf(c1.w, rwv[11], g1);  g2 = fmaf(c1.w, rwv[19], g2);
            g0 = fmaf(c2.x, rwv[4], g0);  g1 = fmaf(c2.x, rwv[12], g1);  g2 = fmaf(c2.x, rwv[20], g2);
            g0 = fmaf(c2.y, rwv[5], g0);  g1 = fmaf(c2.y, rwv[13], g1);  g2 = fmaf(c2.y, rwv[21], g2);
            g0 = fmaf(c2.z, rwv[6], g0);  g1 = fmaf(c2.z, rwv[14], g1);  g2 = fmaf(c2.z, rwv[22], g2);
            g0 = fmaf(c2.w, rwv[7], g0);  g1 = fmaf(c2.w, rwv[15], g1);  g2 = fmaf(c2.w, rwv[23], g2);

            float s2 = S3 * g2;
            float w[9];
            w[0] = g0;
            w[1] = uy * g1; w[2] = uz * g1; w[3] = ux * g1;
            w[4] = s2 * ux * uy;
            w[5] = s2 * uy * uz;
            w[6] = fmaf(1.5f * uz, uz, -0.5f) * g2;
            w[7] = s2 * ux * uz;
            w[8] = 0.5f * s2 * (ux * ux - uy * uy);

            float d0 = xe[0]*w[0], d1 = xe[1]*w[1], d2 = xe[2]*w[2], d3 = xe[3]*w[3];
            float d4 = xe[4]*w[4], d5 = xe[5]*w[5], d6 = xe[6]*w[6], d7 = xe[7]*w[7];
            float d8 = xe[8]*w[8];

            acc[0] += d0 + C13 * (d1 + d2 + d3) + C15 * (d4 + d5 + d6 + d7 + d8);
            if (!LAST) {
                #define T(a, b) (xe[a] * w[b] + xe[b] * w[a])
                acc[1] += T(0,1) - C15 * T(1,6) - S35 * T(1,8) + S35 * T(2,5) + S35 * T(3,4);
                acc[2] += T(0,2) + S35 * T(1,5) + C25 * T(2,6) + S35 * T(3,7);
                acc[3] += T(0,3) + S35 * T(1,4) + S35 * T(2,7) - C15 * T(3,6) + S35 * T(3,8);
                acc[4] += T(0,4) + IS3 * T(1,3) - C27 * T(4,6) + S37 * T(5,7);
                acc[5] += T(0,5) + IS3 * T(1,2) + S37 * T(4,7) + C17 * T(5,6) - S37 * T(5,8);
                acc[6] += T(0,6) - C13 * d1 + C23 * d2 - C13 * d3
                        - C27 * d4 + C17 * d5 + C27 * d6 + C17 * d7 - C27 * d8;
                acc[7] += T(0,7) + IS3 * T(2,3) + S37 * T(4,5) + C17 * T(6,7) + S37 * T(7,8);
                acc[8] += T(0,8) - IS3 * d1 + IS3 * d3 - S37 * d5 + S37 * d7 - C27 * T(6,8);
                #undef T
            }
            c0 = n0; c1 = n1; c2 = n2;
            t = tn;
        }

        #pragma unroll
        for (int a = 0; a < NACC; ++a) acc[a] += __shfl_xor(acc[a], 32);

        if (half == 0) {
            if (LAST) {
                m[(size_t)n * F + f] = acc[0];
            } else {
                float* mp = m + (size_t)n * KCH * F + f;
                #pragma unroll
                for (int a = 0; a < KCH; ++a) mp[a * F] = acc[a];
            }
        }
    }
}

// one thread per (node, k) row; weights fetched as wave-uniform scalar loads
__global__ __launch_bounds__(256) void node_full(float* __restrict__ x,
                                                 const float* __restrict__ m,
                                                 const float* __restrict__ w1,
                                                 const float* __restrict__ b1,
                                                 const float* __restrict__ w2,
                                                 const float* __restrict__ b2) {
    __shared__ float gs[28][33];
    int t = threadIdx.x;
    int slot = t / 9, k = t - slot * 9;
    int n = blockIdx.x * 28 + slot;
    bool valid = (t < 252) && (n < NN);

    float h[F], o1[F];
    if (valid) {
        const float4* xp = (const float4*)(x + ((size_t)n * KCH + k) * F);
        const float4* mp = (const float4*)(m + ((size_t)n * KCH + k) * F);
        #pragma unroll
        for (int j = 0; j < 8; ++j) {
            float4 a = xp[j], b = mp[j];
            h[4 * j + 0] = a.x + b.x; h[4 * j + 1] = a.y + b.y;
            h[4 * j + 2] = a.z + b.z; h[4 * j + 3] = a.w + b.w;
        }
        #pragma unroll
        for (int fo = 0; fo < F; ++fo) {
            float s = 0.f;
            #pragma unroll
            for (int fi = 0; fi < F; ++fi) s = fmaf(h[fi], w1[fi * F + fo], s);
            o1[fo] = s;
        }
        if (k == 0) {
            #pragma unroll
            for (int j = 0; j < F; ++j) {
                o1[j] += b1[j];
                gs[slot][j] = 1.0f / (1.0f + expf(-o1[j]));
            }
        }
    }
    __syncthreads();
    if (valid) {
        #pragma unroll
        for (int j = 0; j < F; ++j) h[j] = o1[j] * gs[slot][j];
        #pragma unroll
        for (int fo = 0; fo < F; ++fo) {
            float s = (k == 0) ? b2[fo] : 0.f;
            #pragma unroll
            for (int fi = 0; fi < F; ++fi) s = fmaf(h[fi], w2[fi * F + fo], s);
            o1[fo] = s;
        }
        float4* xw = (float4*)(x + ((size_t)n * KCH + k) * F);
        #pragma unroll
        for (int j = 0; j < 8; ++j) {
            float4 a = xw[j];
            a.x += o1[4 * j + 0]; a.y += o1[4 * j + 1];
            a.z += o1[4 * j + 2]; a.w += o1[4 * j + 3];
            xw[j] = a;
        }
    }
}

__global__ __launch_bounds__(256) void node_last(const float* __restrict__ x,
                                                 const float* __restrict__ m1,
                                                 const float* __restrict__ w1,
                                                 const float* __restrict__ b1,
                                                 const float* __restrict__ w2,
                                                 const float* __restrict__ b2,
                                                 float* __restrict__ out) {
    int n = blockIdx.x * 256 + threadIdx.x;
    if (n >= NN) return;
    float h[F], o1[F];
    const float4* xp = (const float4*)(x + (size_t)n * KCH * F);   // row k=0
    const float4* mp = (const float4*)(m1 + (size_t)n * F);
    #pragma unroll
    for (int j = 0; j < 8; ++j) {
        float4 a = xp[j], b = mp[j];
        h[4 * j + 0] = a.x + b.x; h[4 * j + 1] = a.y + b.y;
        h[4 * j + 2] = a.z + b.z; h[4 * j + 3] = a.w + b.w;
    }
    #pragma unroll
    for (int fo = 0; fo < F; ++fo) {
        float s = 0.f;
        #pragma unroll
        for (int fi = 0; fi < F; ++fi) s = fmaf(h[fi], w1[fi * F + fo], s);
        s += b1[fo];
        o1[fo] = s;
    }
    #pragma unroll
    for (int j = 0; j < F; ++j) {
        float g = 1.0f / (1.0f + expf(-o1[j]));
        h[j] = o1[j] * g;
    }
    #pragma unroll
    for (int fo = 0; fo < F; ++fo) {
        float s = b2[fo];
        #pragma unroll
        for (int fi = 0; fi < F; ++fi) s = fmaf(h[fi], w2[fi * F + fo], s);
        o1[fo] = s;
    }
    #pragma unroll
    for (int j = 0; j < F; ++j)
        out[(size_t)n * F + j] = x[(size_t)n * KCH * F + j] + o1[j];
}

extern "C" void kernel_launch(void* const* d_in, const int* in_sizes, int n_in,
                              void* d_out, int out_size, void* d_ws, size_t ws_size,
                              hipStream_t stream) {
    (void)in_sizes; (void)n_in; (void)out_size; (void)ws_size;
    const float* dr    = (const float*)d_in[0];
    const float* embed = (const float*)d_in[1];
    const float* rad_w = (const float*)d_in[2];
    const float* d1w   = (const float*)d_in[3];
    const float* d1b   = (const float*)d_in[4];
    const float* d2w   = (const float*)d_in[5];
    const float* d2b   = (const float*)d_in[6];
    const int*   Z     = (const int*)d_in[7];
    const int*   nidx  = (const int*)d_in[8];
    const int* idx_i = nidx;
    const int* idx_j = nidx + NE;

    float* x = (float*)d_ws;
    float* m = x + (size_t)NN * KCH * F;
    int*   offs = (int*)(m + (size_t)NN * KCH * F);   // NN+1
    int*   head = offs + (NN + 1);                    // NN
    int*   cnt  = head + NN;                          // NN (+pad to 16B)
    float4* erec = (float4*)(cnt + NN + 3);           // 3*NE float4 (live-compacted)
    float* outp = (float*)d_out;

    // CSR build with dead-edge filtering + geometry precompute
    hipMemsetAsync(cnt, 0, NN * sizeof(int), stream);
    hist_kernel<<<(NE + 255) / 256, 256, 0, stream>>>(idx_i, idx_j, dr, cnt);
    scan_kernel<<<1, SCAN_T, 0, stream>>>(cnt, offs, head);
    fill_kernel<<<(NE + 255) / 256, 256, 0, stream>>>(idx_i, idx_j, dr, head, erec);

    init_x<<<(NN * F + 255) / 256, 256, 0, stream>>>(embed, Z, x);

    for (int i = 0; i < 3; ++i) {
        const float* rwi = rad_w + (size_t)i * 3 * 8 * F;
        const float* w1 = d1w + (size_t)i * F * F;
        const float* b1 = d1b + (size_t)i * F;
        const float* w2 = d2w + (size_t)i * F * F;
        const float* b2 = d2b + (size_t)i * F;
        if (i < 2) {
            gather_kernel<0><<<2048, 256, 0, stream>>>(erec, rwi, x, offs, m);
            node_full<<<(NN + 27) / 28, 256, 0, stream>>>(x, m, w1, b1, w2, b2);
        } else {
            gather_kernel<1><<<2048, 256, 0, stream>>>(erec, rwi, x, offs, m);
            node_last<<<(NN + 255) / 256, 256, 0, stream>>>(x, m, w1, b1, w2, b2, outp);
        }
    }
}